// Round 1
// baseline (263.974 us; speedup 1.0000x reference)
//
#include <hip/hip_runtime.h>

// MultiheadSelfAttention w/ RoPE, causal. B=2 S=2048 D=1024 NH=16 HD=64.
// cvt_all -> gemm_qkv (m97-style global_load_lds staging) -> rope
// -> attn (S^T/O^T, no-max softmax, reg-prefetch pipeline,
//          FRAGMENT-LINEAR LDS layout: all hot ds ops are base+lane*16B)
// -> gemm_out.

typedef unsigned short u16;
typedef unsigned int   u32;
typedef unsigned long long u64;
using s16x8 = __attribute__((ext_vector_type(8))) short;  // 8 bf16
using f32x4 = __attribute__((ext_vector_type(4))) float;  // 4 fp32 acc

__device__ __forceinline__ u16 f2bf(float f) {
  union { float f; u32 u; } v; v.f = f;
  return (u16)((v.u + 0x7fffu + ((v.u >> 16) & 1u)) >> 16);  // RNE
}
__device__ __forceinline__ float bf2f(u16 h) {
  union { u32 u; float f; } v; v.u = ((u32)h) << 16;
  return v.f;
}

// async 16B global->LDS (DMA; LDS dest = wave-uniform base + lane*16)
__device__ __forceinline__ void gl2lds(const u16* g, u16* l) {
  __builtin_amdgcn_global_load_lds(
      (const __attribute__((address_space(1))) void*)g,
      (__attribute__((address_space(3))) void*)l, 16, 0, 0);
}

// ---------------------------------------------------------------- cvt (fused)
__global__ __launch_bounds__(256) void cvt_all(
    const float* __restrict__ x,
    const float* __restrict__ wq, const float* __restrict__ wk,
    const float* __restrict__ wv, const float* __restrict__ wo,
    u16* __restrict__ xb, u16* __restrict__ wqb, u16* __restrict__ wkb,
    u16* __restrict__ wvb, u16* __restrict__ wob) {
  int e = (blockIdx.x * 256 + threadIdx.x) * 4;
  const float* src; u16* dst; int off;
  const int XN = 4 << 20;
  if (e < XN) { src = x; dst = xb; off = e; }
  else {
    int t = e - XN; int sel = t >> 20; off = t & ((1 << 20) - 1);
    src = sel == 0 ? wq : sel == 1 ? wk : sel == 2 ? wv : wo;
    dst = sel == 0 ? wqb : sel == 1 ? wkb : sel == 2 ? wvb : wob;
  }
  float4 v = *(const float4*)(src + off);
  ushort4 o;
  o.x = f2bf(v.x); o.y = f2bf(v.y); o.z = f2bf(v.z); o.w = f2bf(v.w);
  *(ushort4*)(dst + off) = o;
}

// ---------------------------------------------------------------- GEMM core
// m97 structure: C[128x128] = A[128xK] . W[128xK]^T, bf16, BK=32.
// LDS tiles [128][32] u16 UNPADDED (required by global_load_lds lane layout).
// Per K-tile: each wave issues 2 A-chunks + 2 B-chunks of 64 lanes x 16B.
__device__ __forceinline__ void gemm_core(
    const u16* __restrict__ A, const u16* __restrict__ W,
    u16* As, u16* Bs, int bm0, int bn0, f32x4 (&acc)[4][4]) {
  const int K = 1024;
  int tid = threadIdx.x;
  int wid = tid >> 6, lane = tid & 63, quad = lane >> 4, l15 = lane & 15;
  int wm = (wid >> 1) * 64, wn = (wid & 1) * 64;
  // chunk = row*4 + col8; LDS u16 offset = chunk*8 (row-major [128][32])
  int ch0 = wid * 128 + lane, ch1 = ch0 + 64;
  int r0 = ch0 >> 2, c0 = (ch0 & 3) * 8;
  int r1 = ch1 >> 2, c1 = (ch1 & 3) * 8;
  const u16* Ab = A + (size_t)bm0 * K;
  const u16* Wb = W + (size_t)bn0 * K;
  u16* lA0 = As + wid * 1024; u16* lA1 = lA0 + 512;  // wave-uniform bases
  u16* lB0 = Bs + wid * 1024; u16* lB1 = lB0 + 512;
  for (int k0 = 0; k0 < K; k0 += 32) {
    __syncthreads();  // prev tile's frag reads done
    gl2lds(Ab + (size_t)r0 * K + k0 + c0, lA0);
    gl2lds(Ab + (size_t)r1 * K + k0 + c1, lA1);
    gl2lds(Wb + (size_t)r0 * K + k0 + c0, lB0);
    gl2lds(Wb + (size_t)r1 * K + k0 + c1, lB1);
    __syncthreads();  // compiler drains vmcnt before barrier
    s16x8 af[4], bf[4];
#pragma unroll
    for (int mi = 0; mi < 4; mi++)
      af[mi] = *(const s16x8*)(As + (wm + mi * 16 + l15) * 32 + quad * 8);
#pragma unroll
    for (int ni = 0; ni < 4; ni++)
      bf[ni] = *(const s16x8*)(Bs + (wn + ni * 16 + l15) * 32 + quad * 8);
#pragma unroll
    for (int mi = 0; mi < 4; mi++)
#pragma unroll
      for (int ni = 0; ni < 4; ni++)
        acc[mi][ni] = __builtin_amdgcn_mfma_f32_16x16x32_bf16(
            af[mi], bf[ni], acc[mi][ni], 0, 0, 0);
  }
}

// ---------------------------------------------------------------- QKV proj
__global__ __launch_bounds__(256) void gemm_qkv(
    const u16* __restrict__ xb,
    const u16* __restrict__ wq, const u16* __restrict__ wk,
    const u16* __restrict__ wv,
    u16* __restrict__ qh, u16* __restrict__ kh, u16* __restrict__ vt) {
  __shared__ __align__(16) u16 As[128 * 32];
  __shared__ __align__(16) u16 Bs[128 * 32];
  int z = blockIdx.z;
  const u16* W = (z == 0) ? wq : (z == 1) ? wk : wv;
  int bm0 = blockIdx.y * 128, bn0 = blockIdx.x * 128;
  f32x4 acc[4][4];
  const f32x4 fz = {0.f, 0.f, 0.f, 0.f};
#pragma unroll
  for (int mi = 0; mi < 4; mi++)
#pragma unroll
    for (int ni = 0; ni < 4; ni++) acc[mi][ni] = fz;
  gemm_core(xb, W, As, Bs, bm0, bn0, acc);
  int tid = threadIdx.x, wid = tid >> 6, lane = tid & 63;
  int quad = lane >> 4, l15 = lane & 15;
  int wm = (wid >> 1) * 64, wn = (wid & 1) * 64;
  if (z < 2) {
    u16* dst = (z == 0) ? qh : kh;
#pragma unroll
    for (int mi = 0; mi < 4; mi++)
#pragma unroll
      for (int ni = 0; ni < 4; ni++)
#pragma unroll
        for (int r = 0; r < 4; r++) {
          int row = bm0 + wm + mi * 16 + quad * 4 + r;
          int col = bn0 + wn + ni * 16 + l15;
          int b = row >> 11, s = row & 2047, h = col >> 6, d = col & 63;
          dst[(((size_t)(b * 16 + h)) * 2048 + s) * 64 + d] =
              f2bf(acc[mi][ni][r]);
        }
  } else {
#pragma unroll
    for (int mi = 0; mi < 4; mi++)
#pragma unroll
      for (int ni = 0; ni < 4; ni++) {
        int row0 = bm0 + wm + mi * 16 + quad * 4;
        int col = bn0 + wn + ni * 16 + l15;
        int b = row0 >> 11, s0 = row0 & 2047, h = col >> 6, d = col & 63;
        u64 pk = (u64)f2bf(acc[mi][ni][0]) |
                 ((u64)f2bf(acc[mi][ni][1]) << 16) |
                 ((u64)f2bf(acc[mi][ni][2]) << 32) |
                 ((u64)f2bf(acc[mi][ni][3]) << 48);
        *(u64*)(vt + (((size_t)(b * 16 + h)) * 64 + d) * 2048 + s0) = pk;
      }
  }
}

// ---------------------------------------------------------------- out proj
__global__ __launch_bounds__(256) void gemm_out(
    const u16* __restrict__ ao, const u16* __restrict__ wo,
    float* __restrict__ out) {
  __shared__ __align__(16) u16 As[128 * 32];
  __shared__ __align__(16) u16 Bs[128 * 32];
  int bm0 = blockIdx.y * 128, bn0 = blockIdx.x * 128;
  f32x4 acc[4][4];
  const f32x4 fz = {0.f, 0.f, 0.f, 0.f};
#pragma unroll
  for (int mi = 0; mi < 4; mi++)
#pragma unroll
    for (int ni = 0; ni < 4; ni++) acc[mi][ni] = fz;
  gemm_core(ao, wo, As, Bs, bm0, bn0, acc);
  int tid = threadIdx.x, wid = tid >> 6, lane = tid & 63;
  int quad = lane >> 4, l15 = lane & 15;
  int wm = (wid >> 1) * 64, wn = (wid & 1) * 64;
#pragma unroll
  for (int mi = 0; mi < 4; mi++)
#pragma unroll
    for (int ni = 0; ni < 4; ni++)
#pragma unroll
      for (int r = 0; r < 4; r++) {
        int row = bm0 + wm + mi * 16 + quad * 4 + r;
        int col = bn0 + wn + ni * 16 + l15;
        out[(size_t)row * 1024 + col] = acc[mi][ni][r];
      }
}

// ---------------------------------------------------------------- RoPE
__global__ __launch_bounds__(256) void rope_k(
    u16* __restrict__ qh, u16* __restrict__ kh, const int* __restrict__ pos) {
  int i = blockIdx.x * 256 + threadIdx.x;
  int pair = i & 31;
  int s = (i >> 5) & 2047;
  int hb = i >> 16;
  float p = (float)pos[s];
  float freq = __expf(-0.28782313662425572f * (float)pair);
  float ang = p * freq, sn, cs;
  sincosf(ang, &sn, &cs);
  size_t base = ((size_t)hb * 2048 + s) * 64 + 2 * pair;
  {
    u32 u = *(const u32*)(qh + base);
    float x1 = bf2f((u16)(u & 0xffff)), x2 = bf2f((u16)(u >> 16));
    float r1 = (x1 * cs - x2 * sn) * 0.125f;
    float r2 = (x1 * sn + x2 * cs) * 0.125f;
    *(u32*)(qh + base) = (u32)f2bf(r1) | ((u32)f2bf(r2) << 16);
  }
  {
    u32 u = *(const u32*)(kh + base);
    float x1 = bf2f((u16)(u & 0xffff)), x2 = bf2f((u16)(u >> 16));
    float r1 = x1 * cs - x2 * sn;
    float r2 = x1 * sn + x2 * cs;
    *(u32*)(kh + base) = (u32)f2bf(r1) | ((u32)f2bf(r2) << 16);
  }
}

// ---------------------------------------------------------------- attention
// S^T = K.Q^T, O^T = V^T.P^T, no-max softmax (|score| bounded).
// Block: 32 q (2 waves qsub) x 64-t tiles split across 2 thalf wave-pairs.
// Grid 2048 = 8 blocks/CU (LDS exactly 20480B x 8 = 160KiB); heavy q-tiles
// launch first (qt = 63 - (bid>>5)); bh = bid&31 keeps 4 heads per XCD (L2).
//
// FRAGMENT-LINEAR LDS: K/V tiles and P^T are stored in MFMA-fragment order so
// every hot ds_read/ds_write is wave-uniform-base + lane*16B (zero bank
// conflicts; the global_load_lds pattern). K-tile chunk map:
//   frag_chunk = (t>>4)*128 + (dcol>>5)*64 + ((dcol>>3)&3)*16 + (t&15)
// so reader wave (thalf,mt,kh) reads chunk g*128 + kh*64 + lane, g=thalf*2+mt.
// V-tile identical with (d, tcol) in place of (t, dcol).

__global__ __launch_bounds__(256, 8) void attn_k(
    const u16* __restrict__ qh, const u16* __restrict__ kh,
    const u16* __restrict__ vt, u16* __restrict__ ao) {
  __shared__ __align__(16) u16 ks[64 * 64];   // K-tile, fragment-linear (8KB)
  __shared__ __align__(16) u16 vs[64 * 64];   // V-tile, fragment-linear (8KB)
  __shared__ __align__(16) u16 pt[4 * 512];   // per-wave P^T frag-linear (4KB)
  int bid = blockIdx.x;
  int bh = bid & 31;
  int qt = 63 - (bid >> 5);              // heavy tiles dispatch first
  int b = bh >> 4, h = bh & 15;
  int tid = threadIdx.x, wid = tid >> 6, lane = tid & 63;
  int quad = lane >> 4, l15 = lane & 15;
  int qsub = wid & 1, thalf = wid >> 1;
  const u16* qbase = qh + (size_t)bh * 2048 * 64;
  const u16* kbase = kh + (size_t)bh * 2048 * 64;
  const u16* vbase = vt + (size_t)bh * 64 * 2048;
  u16* ptw = pt + wid * 512;
  const f32x4 fz = {0.f, 0.f, 0.f, 0.f};
  // staging: thread loads K row (wid*16+l15), 16B at dcol quad*16B (+64B) ->
  // LDS chunks wid*128+lane and wid*128+64+lane (both base+lane*16B linear).
  int grow = wid * 16 + l15;              // global row (t for K, d for V)
  int gcol = quad * 8;                    // u16 col within 64
  u16* kw0 = ks + wid * 1024 + lane * 8;  // = chunk (wid*128+lane)*8
  u16* kw1 = kw0 + 512;                   // = chunk (wid*128+64+lane)*8
  u16* vw0 = vs + wid * 1024 + lane * 8;
  u16* vw1 = vw0 + 512;

  int q0 = qt * 32, q0w = q0 + qsub * 16;
  s16x8 qf0 = *(const s16x8*)(qbase + (size_t)(q0w + l15) * 64 + quad * 8);
  s16x8 qf1 = *(const s16x8*)(qbase + (size_t)(q0w + l15) * 64 + 32 + quad * 8);
  f32x4 acc[4];
#pragma unroll
  for (int md = 0; md < 4; md++) acc[md] = fz;
  float lsum = 0.f;
  int qg = q0w + l15;
  int nt = (qt >> 1) + 1;
  uint4 rk0 = *(const uint4*)(kbase + (size_t)grow * 64 + gcol);
  uint4 rk1 = *(const uint4*)(kbase + (size_t)grow * 64 + gcol + 32);
  uint4 rv0 = *(const uint4*)(vbase + (size_t)grow * 2048 + gcol);
  uint4 rv1 = *(const uint4*)(vbase + (size_t)grow * 2048 + gcol + 32);
  for (int it = 0; it < nt; it++) {
    __syncthreads();
    *(uint4*)kw0 = rk0;
    *(uint4*)kw1 = rk1;
    *(uint4*)vw0 = rv0;
    *(uint4*)vw1 = rv1;
    if (it + 1 < nt) {
      int t1 = (it + 1) << 6;
      rk0 = *(const uint4*)(kbase + (size_t)(t1 + grow) * 64 + gcol);
      rk1 = *(const uint4*)(kbase + (size_t)(t1 + grow) * 64 + gcol + 32);
      rv0 = *(const uint4*)(vbase + (size_t)grow * 2048 + t1 + gcol);
      rv1 = *(const uint4*)(vbase + (size_t)grow * 2048 + t1 + gcol + 32);
    }
    __syncthreads();
    int t0 = it << 6, tb = thalf * 32;
    bool diag = (it == nt - 1);
#pragma unroll
    for (int mt = 0; mt < 2; mt++) {
      const u16* kf = ks + (thalf * 2 + mt) * 1024;
      s16x8 ka0 = *(const s16x8*)(kf + lane * 8);          // linear, 0-conflict
      s16x8 ka1 = *(const s16x8*)(kf + 512 + lane * 8);
      f32x4 st = __builtin_amdgcn_mfma_f32_16x16x32_bf16(ka0, qf0, fz, 0, 0, 0);
      st = __builtin_amdgcn_mfma_f32_16x16x32_bf16(ka1, qf1, st, 0, 0, 0);
      u64 pk = 0;
#pragma unroll
      for (int r = 0; r < 4; r++) {
        float p = __expf(st[r]);
        if (diag) {
          int tg = t0 + tb + mt * 16 + quad * 4 + r;
          if (tg > qg) p = 0.f;
        }
        lsum += p;
        pk |= ((u64)f2bf(p)) << (16 * r);
      }
      // P^T frag layout: u16 addr = ((k>>3)*16 + q)*8 + (k&7); here
      // k0 = mt*16+quad*4, q = l15.
      *(u64*)(ptw + (mt * 32 + (quad >> 1) * 16 + l15) * 8 + (quad & 1) * 4) =
          pk;
    }
    s16x8 pb = *(const s16x8*)(ptw + lane * 8);            // linear, 0-conflict
#pragma unroll
    for (int md = 0; md < 4; md++) {
      s16x8 va = *(const s16x8*)(vs + md * 1024 + thalf * 512 + lane * 8);
      acc[md] = __builtin_amdgcn_mfma_f32_16x16x32_bf16(va, pb, acc[md], 0, 0, 0);
    }
  }
  lsum += __shfl_xor(lsum, 16, 64);
  lsum += __shfl_xor(lsum, 32, 64);
  __syncthreads();
  float* redo = (float*)ks;                // 8KB: 128 lanes x 16 f32
  float* redl = (float*)vs;                // 512B: 128 f32
  if (thalf == 1) {
#pragma unroll
    for (int md = 0; md < 4; md++)
#pragma unroll
      for (int r = 0; r < 4; r++)
        redo[(qsub * 64 + lane) * 16 + md * 4 + r] = acc[md][r];
    redl[qsub * 64 + lane] = lsum;
  }
  __syncthreads();
  if (thalf == 0) {
#pragma unroll
    for (int md = 0; md < 4; md++)
#pragma unroll
      for (int r = 0; r < 4; r++)
        acc[md][r] += redo[(qsub * 64 + lane) * 16 + md * 4 + r];
    lsum += redl[qsub * 64 + lane];
    float rl = 1.0f / lsum;
    // O staging in vs beyond redl region: [16 q][72] u16 per qsub (144B rows,
    // 16B-aligned for the uint4 re-read).
    u16* ow = ((u16*)vs) + 256 + qsub * 16 * 72;
#pragma unroll
    for (int md = 0; md < 4; md++) {
      u64 ok = 0;
#pragma unroll
      for (int r = 0; r < 4; r++)
        ok |= ((u64)f2bf(acc[md][r] * rl)) << (16 * r);
      *(u64*)(ow + l15 * 72 + md * 16 + quad * 4) = ok;
    }
    int qq = lane >> 2, dc = lane & 3;
    uint4 o0 = *(uint4*)(ow + qq * 72 + dc * 16);
    uint4 o1 = *(uint4*)(ow + qq * 72 + dc * 16 + 8);
    size_t orow = (size_t)b * 2048 + q0 + qsub * 16 + qq;
    *(uint4*)(ao + orow * 1024 + h * 64 + dc * 16) = o0;
    *(uint4*)(ao + orow * 1024 + h * 64 + dc * 16 + 8) = o1;
  }
}

// ---------------------------------------------------------------- launch
extern "C" void kernel_launch(void* const* d_in, const int* in_sizes, int n_in,
                              void* d_out, int out_size, void* d_ws,
                              size_t ws_size, hipStream_t stream) {
  const float* x  = (const float*)d_in[0];
  const int* pos  = (const int*)d_in[1];
  const float* Wq = (const float*)d_in[2];
  const float* Wk = (const float*)d_in[3];
  const float* Wv = (const float*)d_in[4];
  const float* Wo = (const float*)d_in[5];
  float* out = (float*)d_out;

  char* ws = (char*)d_ws;
  const size_t MB = 1u << 20;
  u16* xb  = (u16*)(ws);             // 8 MB  [4096][1024] bf16
  u16* wqb = (u16*)(ws + 8 * MB);
  u16* wkb = (u16*)(ws + 10 * MB);
  u16* wvb = (u16*)(ws + 12 * MB);
  u16* wob = (u16*)(ws + 14 * MB);
  u16* qhb = (u16*)(ws + 16 * MB);   // [B][NH][S][HD]
  u16* khb = (u16*)(ws + 24 * MB);
  u16* vtb = (u16*)(ws + 32 * MB);   // [B][NH][HD][S]
  u16* ao  = xb;  // xb dead after gemm_qkv

  cvt_all<<<8192, 256, 0, stream>>>(x, Wq, Wk, Wv, Wo,
                                    xb, wqb, wkb, wvb, wob);
  gemm_qkv<<<dim3(8, 32, 3), 256, 0, stream>>>(xb, wqb, wkb, wvb,
                                               qhb, khb, vtb);
  rope_k<<<8192, 256, 0, stream>>>(qhb, khb, pos);
  attn_k<<<2048, 256, 0, stream>>>(qhb, khb, vtb, ao);
  gemm_out<<<dim3(8, 32), 256, 0, stream>>>(ao, wob, out);
}

// Round 2
// 234.497 us; speedup vs baseline: 1.1257x; 1.1257x over previous
//
#include <hip/hip_runtime.h>

// MultiheadSelfAttention w/ RoPE, causal. B=2 S=2048 D=1024 NH=16 HD=64.
// cvt_all -> gemm_qkv (m97-style global_load_lds staging) -> rope
// -> attn (S^T/O^T, no-max softmax, reg-prefetch pipeline,
//          FRAGMENT-LINEAR LDS layout: all hot ds ops are base+lane*16B)
// -> gemm_out.
//
// R1 lesson: __launch_bounds__(256,8) forced VGPR=32 -> ~51MB/dispatch of
// scratch spill traffic (WRITE_SIZE 8->59MB), 2x regression. Use (256,4):
// allocator lands ~56 VGPR which still ALLOWS 8 blocks/CU (<=64) without
// spilling; LDS 20480B x 8 = 160KiB exactly.

typedef unsigned short u16;
typedef unsigned int   u32;
typedef unsigned long long u64;
using s16x8 = __attribute__((ext_vector_type(8))) short;  // 8 bf16
using f32x4 = __attribute__((ext_vector_type(4))) float;  // 4 fp32 acc

__device__ __forceinline__ u16 f2bf(float f) {
  union { float f; u32 u; } v; v.f = f;
  return (u16)((v.u + 0x7fffu + ((v.u >> 16) & 1u)) >> 16);  // RNE
}
__device__ __forceinline__ float bf2f(u16 h) {
  union { u32 u; float f; } v; v.u = ((u32)h) << 16;
  return v.f;
}

// async 16B global->LDS (DMA; LDS dest = wave-uniform base + lane*16)
__device__ __forceinline__ void gl2lds(const u16* g, u16* l) {
  __builtin_amdgcn_global_load_lds(
      (const __attribute__((address_space(1))) void*)g,
      (__attribute__((address_space(3))) void*)l, 16, 0, 0);
}

// ---------------------------------------------------------------- cvt (fused)
__global__ __launch_bounds__(256) void cvt_all(
    const float* __restrict__ x,
    const float* __restrict__ wq, const float* __restrict__ wk,
    const float* __restrict__ wv, const float* __restrict__ wo,
    u16* __restrict__ xb, u16* __restrict__ wqb, u16* __restrict__ wkb,
    u16* __restrict__ wvb, u16* __restrict__ wob) {
  int e = (blockIdx.x * 256 + threadIdx.x) * 4;
  const float* src; u16* dst; int off;
  const int XN = 4 << 20;
  if (e < XN) { src = x; dst = xb; off = e; }
  else {
    int t = e - XN; int sel = t >> 20; off = t & ((1 << 20) - 1);
    src = sel == 0 ? wq : sel == 1 ? wk : sel == 2 ? wv : wo;
    dst = sel == 0 ? wqb : sel == 1 ? wkb : sel == 2 ? wvb : wob;
  }
  float4 v = *(const float4*)(src + off);
  ushort4 o;
  o.x = f2bf(v.x); o.y = f2bf(v.y); o.z = f2bf(v.z); o.w = f2bf(v.w);
  *(ushort4*)(dst + off) = o;
}

// ---------------------------------------------------------------- GEMM core
// m97 structure: C[128x128] = A[128xK] . W[128xK]^T, bf16, BK=32.
// LDS tiles [128][32] u16 UNPADDED (required by global_load_lds lane layout).
// Per K-tile: each wave issues 2 A-chunks + 2 B-chunks of 64 lanes x 16B.
__device__ __forceinline__ void gemm_core(
    const u16* __restrict__ A, const u16* __restrict__ W,
    u16* As, u16* Bs, int bm0, int bn0, f32x4 (&acc)[4][4]) {
  const int K = 1024;
  int tid = threadIdx.x;
  int wid = tid >> 6, lane = tid & 63, quad = lane >> 4, l15 = lane & 15;
  int wm = (wid >> 1) * 64, wn = (wid & 1) * 64;
  // chunk = row*4 + col8; LDS u16 offset = chunk*8 (row-major [128][32])
  int ch0 = wid * 128 + lane, ch1 = ch0 + 64;
  int r0 = ch0 >> 2, c0 = (ch0 & 3) * 8;
  int r1 = ch1 >> 2, c1 = (ch1 & 3) * 8;
  const u16* Ab = A + (size_t)bm0 * K;
  const u16* Wb = W + (size_t)bn0 * K;
  u16* lA0 = As + wid * 1024; u16* lA1 = lA0 + 512;  // wave-uniform bases
  u16* lB0 = Bs + wid * 1024; u16* lB1 = lB0 + 512;
  for (int k0 = 0; k0 < K; k0 += 32) {
    __syncthreads();  // prev tile's frag reads done
    gl2lds(Ab + (size_t)r0 * K + k0 + c0, lA0);
    gl2lds(Ab + (size_t)r1 * K + k0 + c1, lA1);
    gl2lds(Wb + (size_t)r0 * K + k0 + c0, lB0);
    gl2lds(Wb + (size_t)r1 * K + k0 + c1, lB1);
    __syncthreads();  // compiler drains vmcnt before barrier
    s16x8 af[4], bf[4];
#pragma unroll
    for (int mi = 0; mi < 4; mi++)
      af[mi] = *(const s16x8*)(As + (wm + mi * 16 + l15) * 32 + quad * 8);
#pragma unroll
    for (int ni = 0; ni < 4; ni++)
      bf[ni] = *(const s16x8*)(Bs + (wn + ni * 16 + l15) * 32 + quad * 8);
#pragma unroll
    for (int mi = 0; mi < 4; mi++)
#pragma unroll
      for (int ni = 0; ni < 4; ni++)
        acc[mi][ni] = __builtin_amdgcn_mfma_f32_16x16x32_bf16(
            af[mi], bf[ni], acc[mi][ni], 0, 0, 0);
  }
}

// ---------------------------------------------------------------- QKV proj
__global__ __launch_bounds__(256) void gemm_qkv(
    const u16* __restrict__ xb,
    const u16* __restrict__ wq, const u16* __restrict__ wk,
    const u16* __restrict__ wv,
    u16* __restrict__ qh, u16* __restrict__ kh, u16* __restrict__ vt) {
  __shared__ __align__(16) u16 As[128 * 32];
  __shared__ __align__(16) u16 Bs[128 * 32];
  int z = blockIdx.z;
  const u16* W = (z == 0) ? wq : (z == 1) ? wk : wv;
  int bm0 = blockIdx.y * 128, bn0 = blockIdx.x * 128;
  f32x4 acc[4][4];
  const f32x4 fz = {0.f, 0.f, 0.f, 0.f};
#pragma unroll
  for (int mi = 0; mi < 4; mi++)
#pragma unroll
    for (int ni = 0; ni < 4; ni++) acc[mi][ni] = fz;
  gemm_core(xb, W, As, Bs, bm0, bn0, acc);
  int tid = threadIdx.x, wid = tid >> 6, lane = tid & 63;
  int quad = lane >> 4, l15 = lane & 15;
  int wm = (wid >> 1) * 64, wn = (wid & 1) * 64;
  if (z < 2) {
    u16* dst = (z == 0) ? qh : kh;
#pragma unroll
    for (int mi = 0; mi < 4; mi++)
#pragma unroll
      for (int ni = 0; ni < 4; ni++)
#pragma unroll
        for (int r = 0; r < 4; r++) {
          int row = bm0 + wm + mi * 16 + quad * 4 + r;
          int col = bn0 + wn + ni * 16 + l15;
          int b = row >> 11, s = row & 2047, h = col >> 6, d = col & 63;
          dst[(((size_t)(b * 16 + h)) * 2048 + s) * 64 + d] =
              f2bf(acc[mi][ni][r]);
        }
  } else {
#pragma unroll
    for (int mi = 0; mi < 4; mi++)
#pragma unroll
      for (int ni = 0; ni < 4; ni++) {
        int row0 = bm0 + wm + mi * 16 + quad * 4;
        int col = bn0 + wn + ni * 16 + l15;
        int b = row0 >> 11, s0 = row0 & 2047, h = col >> 6, d = col & 63;
        u64 pk = (u64)f2bf(acc[mi][ni][0]) |
                 ((u64)f2bf(acc[mi][ni][1]) << 16) |
                 ((u64)f2bf(acc[mi][ni][2]) << 32) |
                 ((u64)f2bf(acc[mi][ni][3]) << 48);
        *(u64*)(vt + (((size_t)(b * 16 + h)) * 64 + d) * 2048 + s0) = pk;
      }
  }
}

// ---------------------------------------------------------------- out proj
__global__ __launch_bounds__(256) void gemm_out(
    const u16* __restrict__ ao, const u16* __restrict__ wo,
    float* __restrict__ out) {
  __shared__ __align__(16) u16 As[128 * 32];
  __shared__ __align__(16) u16 Bs[128 * 32];
  int bm0 = blockIdx.y * 128, bn0 = blockIdx.x * 128;
  f32x4 acc[4][4];
  const f32x4 fz = {0.f, 0.f, 0.f, 0.f};
#pragma unroll
  for (int mi = 0; mi < 4; mi++)
#pragma unroll
    for (int ni = 0; ni < 4; ni++) acc[mi][ni] = fz;
  gemm_core(ao, wo, As, Bs, bm0, bn0, acc);
  int tid = threadIdx.x, wid = tid >> 6, lane = tid & 63;
  int quad = lane >> 4, l15 = lane & 15;
  int wm = (wid >> 1) * 64, wn = (wid & 1) * 64;
#pragma unroll
  for (int mi = 0; mi < 4; mi++)
#pragma unroll
    for (int ni = 0; ni < 4; ni++)
#pragma unroll
      for (int r = 0; r < 4; r++) {
        int row = bm0 + wm + mi * 16 + quad * 4 + r;
        int col = bn0 + wn + ni * 16 + l15;
        out[(size_t)row * 1024 + col] = acc[mi][ni][r];
      }
}

// ---------------------------------------------------------------- RoPE
__global__ __launch_bounds__(256) void rope_k(
    u16* __restrict__ qh, u16* __restrict__ kh, const int* __restrict__ pos) {
  int i = blockIdx.x * 256 + threadIdx.x;
  int pair = i & 31;
  int s = (i >> 5) & 2047;
  int hb = i >> 16;
  float p = (float)pos[s];
  float freq = __expf(-0.28782313662425572f * (float)pair);
  float ang = p * freq, sn, cs;
  sincosf(ang, &sn, &cs);
  size_t base = ((size_t)hb * 2048 + s) * 64 + 2 * pair;
  {
    u32 u = *(const u32*)(qh + base);
    float x1 = bf2f((u16)(u & 0xffff)), x2 = bf2f((u16)(u >> 16));
    float r1 = (x1 * cs - x2 * sn) * 0.125f;
    float r2 = (x1 * sn + x2 * cs) * 0.125f;
    *(u32*)(qh + base) = (u32)f2bf(r1) | ((u32)f2bf(r2) << 16);
  }
  {
    u32 u = *(const u32*)(kh + base);
    float x1 = bf2f((u16)(u & 0xffff)), x2 = bf2f((u16)(u >> 16));
    float r1 = x1 * cs - x2 * sn;
    float r2 = x1 * sn + x2 * cs;
    *(u32*)(kh + base) = (u32)f2bf(r1) | ((u32)f2bf(r2) << 16);
  }
}

// ---------------------------------------------------------------- attention
// S^T = K.Q^T, O^T = V^T.P^T, no-max softmax (|score| bounded).
// Block: 32 q (2 waves qsub) x 64-t tiles split across 2 thalf wave-pairs.
// Grid 2048; LDS 20480B -> up to 8 blocks/CU when VGPR<=64 (no forced
// occupancy: launch_bounds(256,4) avoids R1's spill catastrophe).
// Heavy q-tiles launch first (qt = 63 - (bid>>5)); bh = bid&31 keeps 4
// heads per XCD (L2).
//
// FRAGMENT-LINEAR LDS: K/V tiles and P^T are stored in MFMA-fragment order so
// every hot ds_read/ds_write is wave-uniform-base + lane*16B (zero bank
// conflicts; the global_load_lds pattern). K-tile chunk map:
//   frag_chunk = (t>>4)*128 + (dcol>>5)*64 + ((dcol>>3)&3)*16 + (t&15)
// so reader wave (thalf,mt,kh) reads chunk g*128 + kh*64 + lane, g=thalf*2+mt.
// V-tile identical with (d, tcol) in place of (t, dcol).

__global__ __launch_bounds__(256, 4) void attn_k(
    const u16* __restrict__ qh, const u16* __restrict__ kh,
    const u16* __restrict__ vt, u16* __restrict__ ao) {
  __shared__ __align__(16) u16 ks[64 * 64];   // K-tile, fragment-linear (8KB)
  __shared__ __align__(16) u16 vs[64 * 64];   // V-tile, fragment-linear (8KB)
  __shared__ __align__(16) u16 pt[4 * 512];   // per-wave P^T frag-linear (4KB)
  int bid = blockIdx.x;
  int bh = bid & 31;
  int qt = 63 - (bid >> 5);              // heavy tiles dispatch first
  int b = bh >> 4, h = bh & 15;
  int tid = threadIdx.x, wid = tid >> 6, lane = tid & 63;
  int quad = lane >> 4, l15 = lane & 15;
  int qsub = wid & 1, thalf = wid >> 1;
  const u16* qbase = qh + (size_t)bh * 2048 * 64;
  const u16* kbase = kh + (size_t)bh * 2048 * 64;
  const u16* vbase = vt + (size_t)bh * 64 * 2048;
  u16* ptw = pt + wid * 512;
  const f32x4 fz = {0.f, 0.f, 0.f, 0.f};
  // staging: thread loads K row (wid*16+l15), 16B at dcol quad*16B (+64B) ->
  // LDS chunks wid*128+lane and wid*128+64+lane (both base+lane*16B linear).
  int grow = wid * 16 + l15;              // global row (t for K, d for V)
  int gcol = quad * 8;                    // u16 col within 64
  u16* kw0 = ks + wid * 1024 + lane * 8;  // = chunk (wid*128+lane)*8
  u16* kw1 = kw0 + 512;                   // = chunk (wid*128+64+lane)*8
  u16* vw0 = vs + wid * 1024 + lane * 8;
  u16* vw1 = vw0 + 512;

  int q0 = qt * 32, q0w = q0 + qsub * 16;
  s16x8 qf0 = *(const s16x8*)(qbase + (size_t)(q0w + l15) * 64 + quad * 8);
  s16x8 qf1 = *(const s16x8*)(qbase + (size_t)(q0w + l15) * 64 + 32 + quad * 8);
  f32x4 acc[4];
#pragma unroll
  for (int md = 0; md < 4; md++) acc[md] = fz;
  float lsum = 0.f;
  int qg = q0w + l15;
  int nt = (qt >> 1) + 1;
  uint4 rk0 = *(const uint4*)(kbase + (size_t)grow * 64 + gcol);
  uint4 rk1 = *(const uint4*)(kbase + (size_t)grow * 64 + gcol + 32);
  uint4 rv0 = *(const uint4*)(vbase + (size_t)grow * 2048 + gcol);
  uint4 rv1 = *(const uint4*)(vbase + (size_t)grow * 2048 + gcol + 32);
  for (int it = 0; it < nt; it++) {
    __syncthreads();
    *(uint4*)kw0 = rk0;
    *(uint4*)kw1 = rk1;
    *(uint4*)vw0 = rv0;
    *(uint4*)vw1 = rv1;
    if (it + 1 < nt) {
      int t1 = (it + 1) << 6;
      rk0 = *(const uint4*)(kbase + (size_t)(t1 + grow) * 64 + gcol);
      rk1 = *(const uint4*)(kbase + (size_t)(t1 + grow) * 64 + gcol + 32);
      rv0 = *(const uint4*)(vbase + (size_t)grow * 2048 + t1 + gcol);
      rv1 = *(const uint4*)(vbase + (size_t)grow * 2048 + t1 + gcol + 32);
    }
    __syncthreads();
    int t0 = it << 6, tb = thalf * 32;
    bool diag = (it == nt - 1);
#pragma unroll
    for (int mt = 0; mt < 2; mt++) {
      const u16* kf = ks + (thalf * 2 + mt) * 1024;
      s16x8 ka0 = *(const s16x8*)(kf + lane * 8);          // linear, 0-conflict
      s16x8 ka1 = *(const s16x8*)(kf + 512 + lane * 8);
      f32x4 st = __builtin_amdgcn_mfma_f32_16x16x32_bf16(ka0, qf0, fz, 0, 0, 0);
      st = __builtin_amdgcn_mfma_f32_16x16x32_bf16(ka1, qf1, st, 0, 0, 0);
      u64 pk = 0;
#pragma unroll
      for (int r = 0; r < 4; r++) {
        float p = __expf(st[r]);
        if (diag) {
          int tg = t0 + tb + mt * 16 + quad * 4 + r;
          if (tg > qg) p = 0.f;
        }
        lsum += p;
        pk |= ((u64)f2bf(p)) << (16 * r);
      }
      // P^T frag layout: u16 addr = ((k>>3)*16 + q)*8 + (k&7); here
      // k0 = mt*16+quad*4, q = l15.
      *(u64*)(ptw + (mt * 32 + (quad >> 1) * 16 + l15) * 8 + (quad & 1) * 4) =
          pk;
    }
    s16x8 pb = *(const s16x8*)(ptw + lane * 8);            // linear, 0-conflict
#pragma unroll
    for (int md = 0; md < 4; md++) {
      s16x8 va = *(const s16x8*)(vs + md * 1024 + thalf * 512 + lane * 8);
      acc[md] = __builtin_amdgcn_mfma_f32_16x16x32_bf16(va, pb, acc[md], 0, 0, 0);
    }
  }
  lsum += __shfl_xor(lsum, 16, 64);
  lsum += __shfl_xor(lsum, 32, 64);
  __syncthreads();
  float* redo = (float*)ks;                // 8KB: 128 lanes x 16 f32
  float* redl = (float*)vs;                // 512B: 128 f32
  if (thalf == 1) {
#pragma unroll
    for (int md = 0; md < 4; md++)
#pragma unroll
      for (int r = 0; r < 4; r++)
        redo[(qsub * 64 + lane) * 16 + md * 4 + r] = acc[md][r];
    redl[qsub * 64 + lane] = lsum;
  }
  __syncthreads();
  if (thalf == 0) {
#pragma unroll
    for (int md = 0; md < 4; md++)
#pragma unroll
      for (int r = 0; r < 4; r++)
        acc[md][r] += redo[(qsub * 64 + lane) * 16 + md * 4 + r];
    lsum += redl[qsub * 64 + lane];
    float rl = 1.0f / lsum;
    // O staging in vs beyond redl region: [16 q][72] u16 per qsub (144B rows,
    // 16B-aligned for the uint4 re-read).
    u16* ow = ((u16*)vs) + 256 + qsub * 16 * 72;
#pragma unroll
    for (int md = 0; md < 4; md++) {
      u64 ok = 0;
#pragma unroll
      for (int r = 0; r < 4; r++)
        ok |= ((u64)f2bf(acc[md][r] * rl)) << (16 * r);
      *(u64*)(ow + l15 * 72 + md * 16 + quad * 4) = ok;
    }
    int qq = lane >> 2, dc = lane & 3;
    uint4 o0 = *(uint4*)(ow + qq * 72 + dc * 16);
    uint4 o1 = *(uint4*)(ow + qq * 72 + dc * 16 + 8);
    size_t orow = (size_t)b * 2048 + q0 + qsub * 16 + qq;
    *(uint4*)(ao + orow * 1024 + h * 64 + dc * 16) = o0;
    *(uint4*)(ao + orow * 1024 + h * 64 + dc * 16 + 8) = o1;
  }
}

// ---------------------------------------------------------------- launch
extern "C" void kernel_launch(void* const* d_in, const int* in_sizes, int n_in,
                              void* d_out, int out_size, void* d_ws,
                              size_t ws_size, hipStream_t stream) {
  const float* x  = (const float*)d_in[0];
  const int* pos  = (const int*)d_in[1];
  const float* Wq = (const float*)d_in[2];
  const float* Wk = (const float*)d_in[3];
  const float* Wv = (const float*)d_in[4];
  const float* Wo = (const float*)d_in[5];
  float* out = (float*)d_out;

  char* ws = (char*)d_ws;
  const size_t MB = 1u << 20;
  u16* xb  = (u16*)(ws);             // 8 MB  [4096][1024] bf16
  u16* wqb = (u16*)(ws + 8 * MB);
  u16* wkb = (u16*)(ws + 10 * MB);
  u16* wvb = (u16*)(ws + 12 * MB);
  u16* wob = (u16*)(ws + 14 * MB);
  u16* qhb = (u16*)(ws + 16 * MB);   // [B][NH][S][HD]
  u16* khb = (u16*)(ws + 24 * MB);
  u16* vtb = (u16*)(ws + 32 * MB);   // [B][NH][HD][S]
  u16* ao  = xb;  // xb dead after gemm_qkv

  cvt_all<<<8192, 256, 0, stream>>>(x, Wq, Wk, Wv, Wo,
                                    xb, wqb, wkb, wvb, wob);
  gemm_qkv<<<dim3(8, 32, 3), 256, 0, stream>>>(xb, wqb, wkb, wvb,
                                               qhb, khb, vtb);
  rope_k<<<8192, 256, 0, stream>>>(qhb, khb, pos);
  attn_k<<<2048, 256, 0, stream>>>(qhb, khb, vtb, ao);
  gemm_out<<<dim3(8, 32), 256, 0, stream>>>(ao, wob, out);
}

// Round 3
// 232.801 us; speedup vs baseline: 1.1339x; 1.0073x over previous
//
#include <hip/hip_runtime.h>

// MultiheadSelfAttention w/ RoPE, causal. B=2 S=2048 D=1024 NH=16 HD=64.
// cvt_all -> gemm_qkv (m97-style global_load_lds staging) -> rope
// -> attn (S^T/O^T, no-max softmax, DOUBLE-BUFFERED single-barrier pipeline,
//          fragment-linear LDS) -> gemm_out.
//
// R1 lesson: forcing 8 blocks/CU via launch_bounds spilled (VGPR=32, 51MB
// scratch traffic). R2 lesson: 1-tile-per-block grid 2048 has a load-
// imbalance tail (light blocks drain, heavy block finishes alone) -> +43%.
// R3: back to grid 1024 w/ 2-phase pairing (uniform ~33 iters/block,
// 4 blocks/CU), double-buffered K/V (36KB LDS), ONE barrier/iter, prefetch
// issued AFTER the barrier so its vmcnt-wait lands at the NEXT iteration's
// ds_write (full compute phase hides global latency; __syncthreads drains
// vmcnt, so issuing before the barrier hides nothing).

typedef unsigned short u16;
typedef unsigned int   u32;
typedef unsigned long long u64;
using s16x8 = __attribute__((ext_vector_type(8))) short;  // 8 bf16
using f32x4 = __attribute__((ext_vector_type(4))) float;  // 4 fp32 acc

__device__ __forceinline__ u16 f2bf(float f) {
  union { float f; u32 u; } v; v.f = f;
  return (u16)((v.u + 0x7fffu + ((v.u >> 16) & 1u)) >> 16);  // RNE
}
__device__ __forceinline__ float bf2f(u16 h) {
  union { u32 u; float f; } v; v.u = ((u32)h) << 16;
  return v.f;
}

// async 16B global->LDS (DMA; LDS dest = wave-uniform base + lane*16)
__device__ __forceinline__ void gl2lds(const u16* g, u16* l) {
  __builtin_amdgcn_global_load_lds(
      (const __attribute__((address_space(1))) void*)g,
      (__attribute__((address_space(3))) void*)l, 16, 0, 0);
}

// ---------------------------------------------------------------- cvt (fused)
__global__ __launch_bounds__(256) void cvt_all(
    const float* __restrict__ x,
    const float* __restrict__ wq, const float* __restrict__ wk,
    const float* __restrict__ wv, const float* __restrict__ wo,
    u16* __restrict__ xb, u16* __restrict__ wqb, u16* __restrict__ wkb,
    u16* __restrict__ wvb, u16* __restrict__ wob) {
  int e = (blockIdx.x * 256 + threadIdx.x) * 4;
  const float* src; u16* dst; int off;
  const int XN = 4 << 20;
  if (e < XN) { src = x; dst = xb; off = e; }
  else {
    int t = e - XN; int sel = t >> 20; off = t & ((1 << 20) - 1);
    src = sel == 0 ? wq : sel == 1 ? wk : sel == 2 ? wv : wo;
    dst = sel == 0 ? wqb : sel == 1 ? wkb : sel == 2 ? wvb : wob;
  }
  float4 v = *(const float4*)(src + off);
  ushort4 o;
  o.x = f2bf(v.x); o.y = f2bf(v.y); o.z = f2bf(v.z); o.w = f2bf(v.w);
  *(ushort4*)(dst + off) = o;
}

// ---------------------------------------------------------------- GEMM core
// m97 structure: C[128x128] = A[128xK] . W[128xK]^T, bf16, BK=32.
// LDS tiles [128][32] u16 UNPADDED (required by global_load_lds lane layout).
// Per K-tile: each wave issues 2 A-chunks + 2 B-chunks of 64 lanes x 16B.
__device__ __forceinline__ void gemm_core(
    const u16* __restrict__ A, const u16* __restrict__ W,
    u16* As, u16* Bs, int bm0, int bn0, f32x4 (&acc)[4][4]) {
  const int K = 1024;
  int tid = threadIdx.x;
  int wid = tid >> 6, lane = tid & 63, quad = lane >> 4, l15 = lane & 15;
  int wm = (wid >> 1) * 64, wn = (wid & 1) * 64;
  // chunk = row*4 + col8; LDS u16 offset = chunk*8 (row-major [128][32])
  int ch0 = wid * 128 + lane, ch1 = ch0 + 64;
  int r0 = ch0 >> 2, c0 = (ch0 & 3) * 8;
  int r1 = ch1 >> 2, c1 = (ch1 & 3) * 8;
  const u16* Ab = A + (size_t)bm0 * K;
  const u16* Wb = W + (size_t)bn0 * K;
  u16* lA0 = As + wid * 1024; u16* lA1 = lA0 + 512;  // wave-uniform bases
  u16* lB0 = Bs + wid * 1024; u16* lB1 = lB0 + 512;
  for (int k0 = 0; k0 < K; k0 += 32) {
    __syncthreads();  // prev tile's frag reads done
    gl2lds(Ab + (size_t)r0 * K + k0 + c0, lA0);
    gl2lds(Ab + (size_t)r1 * K + k0 + c1, lA1);
    gl2lds(Wb + (size_t)r0 * K + k0 + c0, lB0);
    gl2lds(Wb + (size_t)r1 * K + k0 + c1, lB1);
    __syncthreads();  // compiler drains vmcnt before barrier
    s16x8 af[4], bf[4];
#pragma unroll
    for (int mi = 0; mi < 4; mi++)
      af[mi] = *(const s16x8*)(As + (wm + mi * 16 + l15) * 32 + quad * 8);
#pragma unroll
    for (int ni = 0; ni < 4; ni++)
      bf[ni] = *(const s16x8*)(Bs + (wn + ni * 16 + l15) * 32 + quad * 8);
#pragma unroll
    for (int mi = 0; mi < 4; mi++)
#pragma unroll
      for (int ni = 0; ni < 4; ni++)
        acc[mi][ni] = __builtin_amdgcn_mfma_f32_16x16x32_bf16(
            af[mi], bf[ni], acc[mi][ni], 0, 0, 0);
  }
}

// ---------------------------------------------------------------- QKV proj
__global__ __launch_bounds__(256) void gemm_qkv(
    const u16* __restrict__ xb,
    const u16* __restrict__ wq, const u16* __restrict__ wk,
    const u16* __restrict__ wv,
    u16* __restrict__ qh, u16* __restrict__ kh, u16* __restrict__ vt) {
  __shared__ __align__(16) u16 As[128 * 32];
  __shared__ __align__(16) u16 Bs[128 * 32];
  int z = blockIdx.z;
  const u16* W = (z == 0) ? wq : (z == 1) ? wk : wv;
  int bm0 = blockIdx.y * 128, bn0 = blockIdx.x * 128;
  f32x4 acc[4][4];
  const f32x4 fz = {0.f, 0.f, 0.f, 0.f};
#pragma unroll
  for (int mi = 0; mi < 4; mi++)
#pragma unroll
    for (int ni = 0; ni < 4; ni++) acc[mi][ni] = fz;
  gemm_core(xb, W, As, Bs, bm0, bn0, acc);
  int tid = threadIdx.x, wid = tid >> 6, lane = tid & 63;
  int quad = lane >> 4, l15 = lane & 15;
  int wm = (wid >> 1) * 64, wn = (wid & 1) * 64;
  if (z < 2) {
    u16* dst = (z == 0) ? qh : kh;
#pragma unroll
    for (int mi = 0; mi < 4; mi++)
#pragma unroll
      for (int ni = 0; ni < 4; ni++)
#pragma unroll
        for (int r = 0; r < 4; r++) {
          int row = bm0 + wm + mi * 16 + quad * 4 + r;
          int col = bn0 + wn + ni * 16 + l15;
          int b = row >> 11, s = row & 2047, h = col >> 6, d = col & 63;
          dst[(((size_t)(b * 16 + h)) * 2048 + s) * 64 + d] =
              f2bf(acc[mi][ni][r]);
        }
  } else {
#pragma unroll
    for (int mi = 0; mi < 4; mi++)
#pragma unroll
      for (int ni = 0; ni < 4; ni++) {
        int row0 = bm0 + wm + mi * 16 + quad * 4;
        int col = bn0 + wn + ni * 16 + l15;
        int b = row0 >> 11, s0 = row0 & 2047, h = col >> 6, d = col & 63;
        u64 pk = (u64)f2bf(acc[mi][ni][0]) |
                 ((u64)f2bf(acc[mi][ni][1]) << 16) |
                 ((u64)f2bf(acc[mi][ni][2]) << 32) |
                 ((u64)f2bf(acc[mi][ni][3]) << 48);
        *(u64*)(vt + (((size_t)(b * 16 + h)) * 64 + d) * 2048 + s0) = pk;
      }
  }
}

// ---------------------------------------------------------------- out proj
__global__ __launch_bounds__(256) void gemm_out(
    const u16* __restrict__ ao, const u16* __restrict__ wo,
    float* __restrict__ out) {
  __shared__ __align__(16) u16 As[128 * 32];
  __shared__ __align__(16) u16 Bs[128 * 32];
  int bm0 = blockIdx.y * 128, bn0 = blockIdx.x * 128;
  f32x4 acc[4][4];
  const f32x4 fz = {0.f, 0.f, 0.f, 0.f};
#pragma unroll
  for (int mi = 0; mi < 4; mi++)
#pragma unroll
    for (int ni = 0; ni < 4; ni++) acc[mi][ni] = fz;
  gemm_core(ao, wo, As, Bs, bm0, bn0, acc);
  int tid = threadIdx.x, wid = tid >> 6, lane = tid & 63;
  int quad = lane >> 4, l15 = lane & 15;
  int wm = (wid >> 1) * 64, wn = (wid & 1) * 64;
#pragma unroll
  for (int mi = 0; mi < 4; mi++)
#pragma unroll
    for (int ni = 0; ni < 4; ni++)
#pragma unroll
      for (int r = 0; r < 4; r++) {
        int row = bm0 + wm + mi * 16 + quad * 4 + r;
        int col = bn0 + wn + ni * 16 + l15;
        out[(size_t)row * 1024 + col] = acc[mi][ni][r];
      }
}

// ---------------------------------------------------------------- RoPE
__global__ __launch_bounds__(256) void rope_k(
    u16* __restrict__ qh, u16* __restrict__ kh, const int* __restrict__ pos) {
  int i = blockIdx.x * 256 + threadIdx.x;
  int pair = i & 31;
  int s = (i >> 5) & 2047;
  int hb = i >> 16;
  float p = (float)pos[s];
  float freq = __expf(-0.28782313662425572f * (float)pair);
  float ang = p * freq, sn, cs;
  sincosf(ang, &sn, &cs);
  size_t base = ((size_t)hb * 2048 + s) * 64 + 2 * pair;
  {
    u32 u = *(const u32*)(qh + base);
    float x1 = bf2f((u16)(u & 0xffff)), x2 = bf2f((u16)(u >> 16));
    float r1 = (x1 * cs - x2 * sn) * 0.125f;
    float r2 = (x1 * sn + x2 * cs) * 0.125f;
    *(u32*)(qh + base) = (u32)f2bf(r1) | ((u32)f2bf(r2) << 16);
  }
  {
    u32 u = *(const u32*)(kh + base);
    float x1 = bf2f((u16)(u & 0xffff)), x2 = bf2f((u16)(u >> 16));
    float r1 = x1 * cs - x2 * sn;
    float r2 = x1 * sn + x2 * cs;
    *(u32*)(kh + base) = (u32)f2bf(r1) | ((u32)f2bf(r2) << 16);
  }
}

// ---------------------------------------------------------------- attention
// S^T = K.Q^T, O^T = V^T.P^T, no-max softmax (|score| bounded).
// Block: 32 q (2 waves qsub) x 64-t tiles split across 2 thalf wave-pairs.
// Grid 1024 = 4 blocks/CU, 2-phase pairing (qt = pi, then 63-pi) -> every
// block does ~33 uniform iterations: zero load-imbalance tail.
// K/V tiles DOUBLE-BUFFERED (36KB LDS total): one __syncthreads per
// iteration; global prefetch issued after the barrier so its latency is
// hidden by the full compute phase (vmcnt-wait lands at next ds_write).
//
// FRAGMENT-LINEAR LDS: K/V tiles and P^T in MFMA-fragment order; every hot
// ds_read/ds_write is wave-uniform-base + lane*16B (zero bank conflicts).
//   writer (wid,lane): K[wid*16+l15][quad*8 (+32)] -> chunk wid*128+lane (+64)
//   reader (g=thalf*2+mt, lane): chunk g*128+lane (+64) = K[g*16+l15][quad*8 (+32)]

__global__ __launch_bounds__(256, 4) void attn_k(
    const u16* __restrict__ qh, const u16* __restrict__ kh,
    const u16* __restrict__ vt, u16* __restrict__ ao) {
  __shared__ __align__(16) u16 ks[2 * 64 * 64];  // K-tile dbuf (16KB)
  __shared__ __align__(16) u16 vs[2 * 64 * 64];  // V-tile dbuf (16KB)
  __shared__ __align__(16) u16 pt[4 * 512];      // per-wave P^T (4KB)
  int bid = blockIdx.x;
  int bh = bid & 31, pi = bid >> 5;
  int b = bh >> 4, h = bh & 15;
  int tid = threadIdx.x, wid = tid >> 6, lane = tid & 63;
  int quad = lane >> 4, l15 = lane & 15;
  int qsub = wid & 1, thalf = wid >> 1;
  const u16* qbase = qh + (size_t)bh * 2048 * 64;
  const u16* kbase = kh + (size_t)bh * 2048 * 64;
  const u16* vbase = vt + (size_t)bh * 64 * 2048;
  u16* ptw = pt + wid * 512;
  const f32x4 fz = {0.f, 0.f, 0.f, 0.f};
  int grow = wid * 16 + l15;              // global row (t for K, d for V)
  int gcol = quad * 8;                    // u16 col within 64
  int stoff = wid * 1024 + lane * 8;      // staging offset within a buffer

#pragma unroll
  for (int phase = 0; phase < 2; phase++) {
    int qt = phase ? (63 - pi) : pi;
    int q0 = qt * 32, q0w = q0 + qsub * 16;
    s16x8 qf0 = *(const s16x8*)(qbase + (size_t)(q0w + l15) * 64 + quad * 8);
    s16x8 qf1 = *(const s16x8*)(qbase + (size_t)(q0w + l15) * 64 + 32 + quad * 8);
    f32x4 acc[4];
#pragma unroll
    for (int md = 0; md < 4; md++) acc[md] = fz;
    float lsum = 0.f;
    int qg = q0w + l15;
    int nt = (qt >> 1) + 1;
    uint4 rk0 = *(const uint4*)(kbase + (size_t)grow * 64 + gcol);
    uint4 rk1 = *(const uint4*)(kbase + (size_t)grow * 64 + gcol + 32);
    uint4 rv0 = *(const uint4*)(vbase + (size_t)grow * 2048 + gcol);
    uint4 rv1 = *(const uint4*)(vbase + (size_t)grow * 2048 + gcol + 32);
    int co = 0;                            // double-buffer u16 offset toggle
    __syncthreads();  // protect buf0 scratch reuse from prev phase epilogue
    for (int it = 0; it < nt; it++) {
      u16* kb = ks + co;
      u16* vb = vs + co;
      *(uint4*)(kb + stoff) = rk0;
      *(uint4*)(kb + stoff + 512) = rk1;
      *(uint4*)(vb + stoff) = rv0;
      *(uint4*)(vb + stoff + 512) = rv1;
      __syncthreads();  // single barrier/iter: buf[co] writes visible; a
                        // wave's prior reads of this buf drained (lgkmcnt)
      if (it + 1 < nt) {  // prefetch AFTER barrier: hidden by compute phase
        int t1 = (it + 1) << 6;
        rk0 = *(const uint4*)(kbase + (size_t)(t1 + grow) * 64 + gcol);
        rk1 = *(const uint4*)(kbase + (size_t)(t1 + grow) * 64 + gcol + 32);
        rv0 = *(const uint4*)(vbase + (size_t)grow * 2048 + t1 + gcol);
        rv1 = *(const uint4*)(vbase + (size_t)grow * 2048 + t1 + gcol + 32);
      }
      int t0 = it << 6, tb = thalf * 32;
      bool diag = (it == nt - 1);
#pragma unroll
      for (int mt = 0; mt < 2; mt++) {
        const u16* kf = kb + (thalf * 2 + mt) * 1024;
        s16x8 ka0 = *(const s16x8*)(kf + lane * 8);        // linear, 0-conflict
        s16x8 ka1 = *(const s16x8*)(kf + 512 + lane * 8);
        f32x4 st = __builtin_amdgcn_mfma_f32_16x16x32_bf16(ka0, qf0, fz, 0, 0, 0);
        st = __builtin_amdgcn_mfma_f32_16x16x32_bf16(ka1, qf1, st, 0, 0, 0);
        u64 pk = 0;
#pragma unroll
        for (int r = 0; r < 4; r++) {
          float p = __expf(st[r]);
          if (diag) {
            int tg = t0 + tb + mt * 16 + quad * 4 + r;
            if (tg > qg) p = 0.f;
          }
          lsum += p;
          pk |= ((u64)f2bf(p)) << (16 * r);
        }
        // P^T frag layout: u16 addr = ((k>>3)*16 + q)*8 + (k&7);
        // k0 = mt*16+quad*4, q = l15.
        *(u64*)(ptw + (mt * 32 + (quad >> 1) * 16 + l15) * 8 + (quad & 1) * 4) =
            pk;
      }
      s16x8 pb = *(const s16x8*)(ptw + lane * 8);          // linear, 0-conflict
#pragma unroll
      for (int md = 0; md < 4; md++) {
        s16x8 va = *(const s16x8*)(vb + md * 1024 + thalf * 512 + lane * 8);
        acc[md] = __builtin_amdgcn_mfma_f32_16x16x32_bf16(va, pb, acc[md], 0, 0, 0);
      }
      co ^= 4096;
    }
    lsum += __shfl_xor(lsum, 16, 64);
    lsum += __shfl_xor(lsum, 32, 64);
    __syncthreads();  // all waves done reading K/V bufs before scratch reuse
    float* redo = (float*)ks;              // buf0 region: 128 lanes x 16 f32
    float* redl = (float*)vs;              // buf0 region: 128 f32
    if (thalf == 1) {
#pragma unroll
      for (int md = 0; md < 4; md++)
#pragma unroll
        for (int r = 0; r < 4; r++)
          redo[(qsub * 64 + lane) * 16 + md * 4 + r] = acc[md][r];
      redl[qsub * 64 + lane] = lsum;
    }
    __syncthreads();
    if (thalf == 0) {
#pragma unroll
      for (int md = 0; md < 4; md++)
#pragma unroll
        for (int r = 0; r < 4; r++)
          acc[md][r] += redo[(qsub * 64 + lane) * 16 + md * 4 + r];
      lsum += redl[qsub * 64 + lane];
      float rl = 1.0f / lsum;
      // O staging in vs past redl: [16 q][72] u16 per qsub (16B-aligned rows)
      u16* ow = ((u16*)vs) + 256 + qsub * 16 * 72;
#pragma unroll
      for (int md = 0; md < 4; md++) {
        u64 ok = 0;
#pragma unroll
        for (int r = 0; r < 4; r++)
          ok |= ((u64)f2bf(acc[md][r] * rl)) << (16 * r);
        *(u64*)(ow + l15 * 72 + md * 16 + quad * 4) = ok;
      }
      int qq = lane >> 2, dc = lane & 3;
      uint4 o0 = *(uint4*)(ow + qq * 72 + dc * 16);
      uint4 o1 = *(uint4*)(ow + qq * 72 + dc * 16 + 8);
      size_t orow = (size_t)b * 2048 + q0 + qsub * 16 + qq;
      *(uint4*)(ao + orow * 1024 + h * 64 + dc * 16) = o0;
      *(uint4*)(ao + orow * 1024 + h * 64 + dc * 16 + 8) = o1;
    }
  }
}

// ---------------------------------------------------------------- launch
extern "C" void kernel_launch(void* const* d_in, const int* in_sizes, int n_in,
                              void* d_out, int out_size, void* d_ws,
                              size_t ws_size, hipStream_t stream) {
  const float* x  = (const float*)d_in[0];
  const int* pos  = (const int*)d_in[1];
  const float* Wq = (const float*)d_in[2];
  const float* Wk = (const float*)d_in[3];
  const float* Wv = (const float*)d_in[4];
  const float* Wo = (const float*)d_in[5];
  float* out = (float*)d_out;

  char* ws = (char*)d_ws;
  const size_t MB = 1u << 20;
  u16* xb  = (u16*)(ws);             // 8 MB  [4096][1024] bf16
  u16* wqb = (u16*)(ws + 8 * MB);
  u16* wkb = (u16*)(ws + 10 * MB);
  u16* wvb = (u16*)(ws + 12 * MB);
  u16* wob = (u16*)(ws + 14 * MB);
  u16* qhb = (u16*)(ws + 16 * MB);   // [B][NH][S][HD]
  u16* khb = (u16*)(ws + 24 * MB);
  u16* vtb = (u16*)(ws + 32 * MB);   // [B][NH][HD][S]
  u16* ao  = xb;  // xb dead after gemm_qkv

  cvt_all<<<8192, 256, 0, stream>>>(x, Wq, Wk, Wv, Wo,
                                    xb, wqb, wkb, wvb, wob);
  gemm_qkv<<<dim3(8, 32, 3), 256, 0, stream>>>(xb, wqb, wkb, wvb,
                                               qhb, khb, vtb);
  rope_k<<<8192, 256, 0, stream>>>(qhb, khb, pos);
  attn_k<<<1024, 256, 0, stream>>>(qhb, khb, vtb, ao);
  gemm_out<<<dim3(8, 32), 256, 0, stream>>>(ao, wob, out);
}